// Round 4
// baseline (8792.648 us; speedup 1.0000x reference)
//
#include <hip/hip_runtime.h>
#include <math.h>

#define NBATCH 8
#define IH 1024
#define IW 1024
#define HW (IH*IW)
#define NTOP 1048
#define TIE_CAP 4096

// trunk tiling: output tile TTS x TTS, halos 7/6/4/1 for x1/x2/x3/x4.
// TTS=18: all stage unit-counts <= 256 (single strip per thread, no loop ->
// no LICM hoisting), LDS 36.6 KB -> 4 blocks/CU.
#define TTS 18
#define TD1 (TTS+14)  // 32  x1 tile rows/cols (valid data)
#define TD2 (TTS+12)  // 30  x2 tile
#define TD3 (TTS+8)   // 26  x3 tile
#define TD4 (TTS+2)   // 20  x4 tile
// odd row strides -> bank-conflict-free (gcd(stride,32)=1)
#define SD1 33
#define SD2 31
#define SD3 27
#define SD4 21
// per-channel sizes (padded +4 so last-strip vector over-reads stay in-array)
#define CH1 (SD1*TD1+4)  // 1060
#define CH2 (SD2*TD2+4)  // 934
#define CH3 (SD3*TD3+4)  // 706
#define CH4 (SD4*TD4+4)  // 424

// refinement tiling
#define RTS 32
#define RD1 (RTS+4)   // 36  J tile (halo 2)
#define RD2 (RTS+2)   // 34  hidden tile (halo 1)

__device__ __forceinline__ float clip01(float v){ return fminf(fmaxf(v, 0.f), 1.f); }

// accumulate KSxKS windows for a 1x4 output strip over 3 source channels.
template<int CH,int SD,int KS,int CIN>
__device__ __forceinline__ void accrow4(float a[3][4], const float (*sx)[CH],
    int base, const float* __restrict__ w, int ci0)
{
#pragma unroll
  for (int ci = 0; ci < 3; ++ci) {
#pragma unroll
    for (int ky = 0; ky < KS; ++ky) {
      float v[KS+3];
      const float* row = &sx[ci][base + ky*SD];
#pragma unroll
      for (int j = 0; j < KS+3; ++j) v[j] = row[j];
#pragma unroll
      for (int o = 0; o < 3; ++o) {
        const float* wp = w + ((o*CIN + ci0+ci)*KS + ky)*KS;
#pragma unroll
        for (int kx = 0; kx < KS; ++kx) {
          float wv = wp[kx];
#pragma unroll
          for (int q = 0; q < 4; ++q)
            a[o][q] = fmaf(v[kx+q], wv, a[o][q]);
        }
      }
    }
  }
}

// ---------------- init small scratch ----------------
__global__ void k_init(unsigned* hr, unsigned* prefix, unsigned* remain,
                       float* overall, unsigned* tie_cnt, float* sum_gt,
                       unsigned* histeq, unsigned* mnb, unsigned* mxb)
{
  int t = threadIdx.x;
  for (int i = t; i < 4*NBATCH*256; i += 256) hr[i] = 0u;
  for (int i = t; i < NBATCH*3*256; i += 256) histeq[i] = 0u;
  if (t < NBATCH) { prefix[t] = 0u; remain[t] = NTOP; overall[t] = 0.f; tie_cnt[t] = 0u; }
  if (t < NBATCH*3) { sum_gt[t] = 0.f; mnb[t] = 0x7f7fffffu; mxb[t] = 0u; }
}

// ---------------- bright = mean_c(clip(x)), overall sum ----------------
__global__ __launch_bounds__(256) void k_bright(const float* __restrict__ x,
    float* __restrict__ bright, float* __restrict__ overall)
{
  __shared__ float sred[256];
  const int b = blockIdx.y;
  const int t = threadIdx.x;
  const float4* c0 = (const float4*)(x + (size_t)b*3*HW);
  const float4* c1 = (const float4*)(x + (size_t)b*3*HW + HW);
  const float4* c2 = (const float4*)(x + (size_t)b*3*HW + 2*(size_t)HW);
  float4* bp = (float4*)(bright + (size_t)b*HW);
  float lsum = 0.f;
  int stride = gridDim.x*blockDim.x;
  for (int i = blockIdx.x*blockDim.x + t; i < HW/4; i += stride) {
    float4 a = c0[i], d = c1[i], e = c2[i];
    float4 br;
    br.x = (clip01(a.x)+clip01(d.x)+clip01(e.x))/3.f;
    br.y = (clip01(a.y)+clip01(d.y)+clip01(e.y))/3.f;
    br.z = (clip01(a.z)+clip01(d.z)+clip01(e.z))/3.f;
    br.w = (clip01(a.w)+clip01(d.w)+clip01(e.w))/3.f;
    bp[i] = br;
    lsum += br.x+br.y+br.z+br.w;
  }
  sred[t] = lsum; __syncthreads();
  for (int s = 128; s > 0; s >>= 1) { if (t < s) sred[t] += sred[t+s]; __syncthreads(); }
  if (t == 0) atomicAdd(&overall[b], sred[0]);
}

// ---------------- fused conv trunk: x -> k ----------------
// __launch_bounds__(256,4): cap at 128 VGPR (16 waves/CU) -> no spills, and
// the allocator is forced to reuse v[] instead of pipelining giant live sets.
__global__ __launch_bounds__(256, 4) void k_trunk(const float* __restrict__ x,
    const float* __restrict__ w1, const float* __restrict__ b1,
    const float* __restrict__ w2, const float* __restrict__ b2,
    const float* __restrict__ w3, const float* __restrict__ b3,
    const float* __restrict__ w4, const float* __restrict__ b4,
    const float* __restrict__ w5, const float* __restrict__ b5,
    float* __restrict__ kout)
{
  __shared__ float s1[3][CH1];
  __shared__ float s2[3][CH2];
  __shared__ float s3[3][CH3];
  __shared__ float s4[3][CH4];
  const int b = blockIdx.z;
  const int gy0 = blockIdx.y*TTS, gx0 = blockIdx.x*TTS;
  const float* xb = x + (size_t)b*3*HW;
  const int tid = threadIdx.x;

  // stage 1: x1 = relu(1x1 conv of clip(x)); zero outside image. TD1^2=1024 = 4 trips.
  for (int idx = tid; idx < TD1*TD1; idx += 256) {
    int iy = idx/TD1, ix = idx - iy*TD1;
    int gy = gy0 - 7 + iy, gx = gx0 - 7 + ix;
    float o0 = 0.f, o1 = 0.f, o2 = 0.f;
    if (gy >= 0 && gy < IH && gx >= 0 && gx < IW) {
      int gi = gy*IW + gx;
      float c0 = clip01(xb[gi]), c1 = clip01(xb[HW+gi]), c2 = clip01(xb[2*HW+gi]);
      o0 = fmaxf(fmaf(w1[0],c0,fmaf(w1[1],c1,fmaf(w1[2],c2,b1[0]))), 0.f);
      o1 = fmaxf(fmaf(w1[3],c0,fmaf(w1[4],c1,fmaf(w1[5],c2,b1[1]))), 0.f);
      o2 = fmaxf(fmaf(w1[6],c0,fmaf(w1[7],c1,fmaf(w1[8],c2,b1[2]))), 0.f);
    }
    int off = iy*SD1 + ix;
    s1[0][off]=o0; s1[1][off]=o1; s1[2][off]=o2;
  }
  __syncthreads();

  // stage 2: x2 = relu(3x3 conv of x1), CIN=3. 240 units <= 256: single strip/thread.
  {
    const int NU = ((TD2+3)/4)*TD2;  // 8*30 = 240
    int u = tid;
    if (u < NU) {
      int iy = u % TD2, ix0 = (u / TD2)*4;
      int gy = gy0 - 6 + iy;
      float a[3][4];
#pragma unroll
      for (int o=0;o<3;++o){float bv=b2[o];a[o][0]=bv;a[o][1]=bv;a[o][2]=bv;a[o][3]=bv;}
      accrow4<CH1,SD1,3,3>(a, s1, iy*SD1 + ix0, w2, 0);
      bool rowok = (gy >= 0 && gy < IH);
#pragma unroll
      for (int q=0;q<4;++q) {
        int ix = ix0+q;
        if (ix < TD2) {
          int gx = gx0 - 6 + ix;
          bool ok = rowok && gx >= 0 && gx < IW;
          int off = iy*SD2 + ix;
          s2[0][off] = ok ? fmaxf(a[0][q],0.f) : 0.f;
          s2[1][off] = ok ? fmaxf(a[1][q],0.f) : 0.f;
          s2[2][off] = ok ? fmaxf(a[2][q],0.f) : 0.f;
        }
      }
    }
  }
  __syncthreads();

  // stage 3: x3 = relu(5x5 conv of [x1,x2]), CIN=6. 182 units.
  {
    const int NU = ((TD3+3)/4)*TD3;  // 7*26 = 182
    int u = tid;
    if (u < NU) {
      int iy = u % TD3, ix0 = (u / TD3)*4;
      int gy = gy0 - 4 + iy;
      float a[3][4];
#pragma unroll
      for (int o=0;o<3;++o){float bv=b3[o];a[o][0]=bv;a[o][1]=bv;a[o][2]=bv;a[o][3]=bv;}
      accrow4<CH1,SD1,5,6>(a, s1, (iy+1)*SD1 + (ix0+1), w3, 0);
      accrow4<CH2,SD2,5,6>(a, s2, iy*SD2 + ix0,         w3, 3);
      bool rowok = (gy >= 0 && gy < IH);
#pragma unroll
      for (int q=0;q<4;++q) {
        int ix = ix0+q;
        if (ix < TD3) {
          int gx = gx0 - 4 + ix;
          bool ok = rowok && gx >= 0 && gx < IW;
          int off = iy*SD3 + ix;
          s3[0][off] = ok ? fmaxf(a[0][q],0.f) : 0.f;
          s3[1][off] = ok ? fmaxf(a[1][q],0.f) : 0.f;
          s3[2][off] = ok ? fmaxf(a[2][q],0.f) : 0.f;
        }
      }
    }
  }
  __syncthreads();

  // stage 4: x4 = relu(7x7 conv of [x2,x3]), CIN=6. 100 units.
  {
    const int NU = ((TD4+3)/4)*TD4;  // 5*20 = 100
    int u = tid;
    if (u < NU) {
      int iy = u % TD4, ix0 = (u / TD4)*4;
      int gy = gy0 - 1 + iy;
      float a[3][4];
#pragma unroll
      for (int o=0;o<3;++o){float bv=b4[o];a[o][0]=bv;a[o][1]=bv;a[o][2]=bv;a[o][3]=bv;}
      accrow4<CH2,SD2,7,6>(a, s2, (iy+2)*SD2 + (ix0+2), w4, 0);
      accrow4<CH3,SD3,7,6>(a, s3, iy*SD3 + ix0,         w4, 3);
      bool rowok = (gy >= 0 && gy < IH);
#pragma unroll
      for (int q=0;q<4;++q) {
        int ix = ix0+q;
        if (ix < TD4) {
          int gx = gx0 - 1 + ix;
          bool ok = rowok && gx >= 0 && gx < IW;
          int off = iy*SD4 + ix;
          s4[0][off] = ok ? fmaxf(a[0][q],0.f) : 0.f;
          s4[1][off] = ok ? fmaxf(a[1][q],0.f) : 0.f;
          s4[2][off] = ok ? fmaxf(a[2][q],0.f) : 0.f;
        }
      }
    }
  }
  __syncthreads();

  // stage 5: k = clip(relu(3x3 conv of [x1,x2,x3,x4]), 0.05, 2). 90 units.
  {
    const int NU = ((TTS+3)/4)*TTS;  // 5*18 = 90
    int u = tid;
    if (u < NU) {
      int iy = u % TTS, ix0 = (u / TTS)*4;
      int gy = gy0 + iy;
      float a[3][4];
#pragma unroll
      for (int o=0;o<3;++o){float bv=b5[o];a[o][0]=bv;a[o][1]=bv;a[o][2]=bv;a[o][3]=bv;}
      accrow4<CH1,SD1,3,12>(a, s1, (iy+6)*SD1 + (ix0+6), w5, 0);
      accrow4<CH2,SD2,3,12>(a, s2, (iy+5)*SD2 + (ix0+5), w5, 3);
      accrow4<CH3,SD3,3,12>(a, s3, (iy+3)*SD3 + (ix0+3), w5, 6);
      accrow4<CH4,SD4,3,12>(a, s4, iy*SD4 + ix0,         w5, 9);
      if (gy < IH) {
#pragma unroll
        for (int q=0;q<4;++q) {
          int ix = ix0+q;
          int gx = gx0 + ix;
          if (ix < TTS && gx < IW) {
            size_t gi = (size_t)gy*IW + gx;
            kout[((size_t)b*3+0)*HW + gi] = fminf(fmaxf(a[0][q], 0.05f), 2.0f);
            kout[((size_t)b*3+1)*HW + gi] = fminf(fmaxf(a[1][q], 0.05f), 2.0f);
            kout[((size_t)b*3+2)*HW + gi] = fminf(fmaxf(a[2][q], 0.05f), 2.0f);
          }
        }
      }
    }
  }
}

// ---------------- radix select (top-NTOP threshold) ----------------
__global__ __launch_bounds__(256) void k_radix_hist(const float* __restrict__ bright,
    const unsigned* __restrict__ prefix, unsigned* __restrict__ hr, int pass)
{
  __shared__ unsigned lh[256];
  const int b = blockIdx.y;
  const int t = threadIdx.x;
  lh[t] = 0u; __syncthreads();
  const unsigned pf = prefix[b];
  const unsigned mask = (pass == 0) ? 0u : (0xFFFFFFFFu << (32 - 8*pass));
  const int shift = 24 - 8*pass;
  const float* br = bright + (size_t)b*HW;
  int stride = gridDim.x*blockDim.x;
  for (int i = blockIdx.x*blockDim.x + t; i < HW; i += stride) {
    unsigned bits = __float_as_uint(br[i]);
    if ((bits & mask) == pf) atomicAdd(&lh[(bits >> shift) & 0xFFu], 1u);
  }
  __syncthreads();
  if (lh[t]) atomicAdd(&hr[(pass*NBATCH + b)*256 + t], lh[t]);
}

__global__ void k_radix_scan(const unsigned* __restrict__ hr,
    unsigned* __restrict__ prefix, unsigned* __restrict__ remain, int pass)
{
  int b = threadIdx.x;
  if (b >= NBATCH) return;
  unsigned rem = remain[b];
  const unsigned* h = hr + (pass*NBATCH + b)*256;
  const int shift = 24 - 8*pass;
  for (int bin = 255; bin >= 0; --bin) {
    unsigned c = h[bin];
    if (rem <= c) { prefix[b] |= ((unsigned)bin) << shift; remain[b] = rem; return; }
    rem -= c;
  }
  remain[b] = rem;
}

// ---------------- gather colors of pixels above/equal threshold ----------------
__global__ __launch_bounds__(256) void k_gather(const float* __restrict__ x,
    const float* __restrict__ bright, const unsigned* __restrict__ prefix,
    float* __restrict__ sum_gt, unsigned* __restrict__ tie_cnt, unsigned* __restrict__ tie_idx)
{
  const int b = blockIdx.y;
  const unsigned T = prefix[b];
  const float* br = bright + (size_t)b*HW;
  int stride = gridDim.x*blockDim.x;
  for (int i = blockIdx.x*blockDim.x + threadIdx.x; i < HW; i += stride) {
    unsigned bits = __float_as_uint(br[i]);
    if (bits > T) {
#pragma unroll
      for (int c = 0; c < 3; ++c)
        atomicAdd(&sum_gt[b*3+c], clip01(x[((size_t)b*3+c)*HW + i]));
    } else if (bits == T) {
      unsigned p = atomicAdd(&tie_cnt[b], 1u);
      if (p < TIE_CAP) tie_idx[b*TIE_CAP + p] = i;
    }
  }
}

// ---------------- finalize A (lowest-index tie-break like lax.top_k) ----------------
__global__ __launch_bounds__(256) void k_afinal(const float* __restrict__ x,
    const float* __restrict__ sum_gt, const unsigned* __restrict__ tie_cnt,
    const unsigned* __restrict__ tie_idx, const unsigned* __restrict__ remain,
    const float* __restrict__ overall, float* __restrict__ A)
{
  __shared__ unsigned sidx[TIE_CAP];
  __shared__ unsigned sred[256];
  __shared__ float ssum[3];
  const int b = blockIdx.x;
  const int t = threadIdx.x;
  unsigned cnt = tie_cnt[b]; if (cnt > TIE_CAP) cnt = TIE_CAP;
  unsigned need = remain[b]; if (need > cnt) need = cnt;
  if (t < 3) ssum[t] = 0.f;
  for (unsigned i = t; i < cnt; i += 256) sidx[i] = tie_idx[b*TIE_CAP + i];
  __syncthreads();
  if (need == cnt) {
    float l0=0.f,l1=0.f,l2=0.f;
    for (unsigned i = t; i < cnt; i += 256) {
      unsigned px = sidx[i];
      l0 += clip01(x[((size_t)b*3+0)*HW + px]);
      l1 += clip01(x[((size_t)b*3+1)*HW + px]);
      l2 += clip01(x[((size_t)b*3+2)*HW + px]);
    }
    atomicAdd(&ssum[0], l0); atomicAdd(&ssum[1], l1); atomicAdd(&ssum[2], l2);
    __syncthreads();
  } else {
    for (unsigned it = 0; it < need; ++it) {
      unsigned lmin = 0xFFFFFFFFu;
      for (unsigned i = t; i < cnt; i += 256) lmin = min(lmin, sidx[i]);
      sred[t] = lmin; __syncthreads();
      for (int s = 128; s > 0; s >>= 1) { if (t < s) sred[t] = min(sred[t], sred[t+s]); __syncthreads(); }
      unsigned mv = sred[0];
      if (t == 0) {
        ssum[0] += clip01(x[((size_t)b*3+0)*HW + mv]);
        ssum[1] += clip01(x[((size_t)b*3+1)*HW + mv]);
        ssum[2] += clip01(x[((size_t)b*3+2)*HW + mv]);
      }
      for (unsigned i = t; i < cnt; i += 256) if (sidx[i] == mv) sidx[i] = 0xFFFFFFFFu;
      __syncthreads();
    }
  }
  __syncthreads();
  if (t < 3) {
    float a = (sum_gt[b*3+t] + ssum[t]) / (float)NTOP;
    float f = fminf(fmaxf(1.2f - overall[b]/(float)HW, 0.8f), 1.5f);
    A[b*3+t] = fminf(fmaxf(a*f, 0.5f), 0.95f);
  }
}

// ---------------- fused J + refinement (3->8->3, 3x3) + blend ----------------
__global__ __launch_bounds__(256) void k_refineJ(const float* __restrict__ x,
    const float* __restrict__ kin, const float* __restrict__ A,
    const float* __restrict__ rw1, const float* __restrict__ rb1,
    const float* __restrict__ rw2, const float* __restrict__ rb2,
    float* __restrict__ out)
{
  __shared__ float sJ[3][RD1*RD1];
  __shared__ float sH[8][RD2*RD2];
  const int b = blockIdx.z;
  const int gy0 = blockIdx.y*RTS, gx0 = blockIdx.x*RTS;
  const int tid = threadIdx.x;
  const float A0 = A[b*3+0], A1 = A[b*3+1], A2 = A[b*3+2];
  const float* xb = x + (size_t)b*3*HW;
  const float* kb = kin + (size_t)b*3*HW;

  for (int idx = tid; idx < RD1*RD1; idx += 256) {
    int iy = idx/RD1, ix = idx - iy*RD1;
    int gy = gy0 - 2 + iy, gx = gx0 - 2 + ix;
    float j0 = 0.f, j1 = 0.f, j2 = 0.f;
    if (gy >= 0 && gy < IH && gx >= 0 && gx < IW) {
      size_t gi = (size_t)gy*IW + gx;
      float c0 = clip01(xb[gi]), c1 = clip01(xb[HW+gi]), c2 = clip01(xb[2*(size_t)HW+gi]);
      float br = (c0+c1+c2)/3.f;
      float st = fminf(fmaxf(1.f-br, 0.3f), 0.8f);
      float t0 = fminf(fmaxf(1.f-st*kb[gi],             0.1f),1.f)+1e-5f;
      float t1 = fminf(fmaxf(1.f-st*kb[HW+gi],          0.1f),1.f)+1e-5f;
      float t2 = fminf(fmaxf(1.f-st*kb[2*(size_t)HW+gi],0.1f),1.f)+1e-5f;
      j0 = (c0-A0)/t0 + A0;
      j1 = (c1-A1)/t1 + A1;
      j2 = (c2-A2)/t2 + A2;
    }
    sJ[0][idx]=j0; sJ[1][idx]=j1; sJ[2][idx]=j2;
  }
  __syncthreads();

  for (int idx = tid; idx < RD2*RD2; idx += 256) {
    int iy = idx/RD2, ix = idx - iy*RD2;
    int gy = gy0 - 1 + iy, gx = gx0 - 1 + ix;
    float acc[8];
#pragma unroll
    for (int o = 0; o < 8; ++o) acc[o] = rb1[o];
    if (gy >= 0 && gy < IH && gx >= 0 && gx < IW) {
#pragma unroll
      for (int ci = 0; ci < 3; ++ci) {
#pragma unroll
        for (int ky = 0; ky < 3; ++ky) {
#pragma unroll
          for (int kx = 0; kx < 3; ++kx) {
            float v = sJ[ci][(iy+ky)*RD1 + ix+kx];
#pragma unroll
            for (int o = 0; o < 8; ++o)
              acc[o] = fmaf(v, rw1[((o*3+ci)*3+ky)*3+kx], acc[o]);
          }
        }
      }
#pragma unroll
      for (int o = 0; o < 8; ++o) sH[o][idx] = fmaxf(acc[o], 0.f);
    } else {
#pragma unroll
      for (int o = 0; o < 8; ++o) sH[o][idx] = 0.f;
    }
  }
  __syncthreads();

  for (int idx = tid; idx < RTS*RTS; idx += 256) {
    int iy = idx/RTS, ix = idx - iy*RTS;
    int gy = gy0 + iy, gx = gx0 + ix;
    float r0 = rb2[0], r1 = rb2[1], r2 = rb2[2];
#pragma unroll
    for (int ci = 0; ci < 8; ++ci) {
#pragma unroll
      for (int ky = 0; ky < 3; ++ky) {
#pragma unroll
        for (int kx = 0; kx < 3; ++kx) {
          float v = sH[ci][(iy+ky)*RD2 + ix+kx];
          r0 = fmaf(v, rw2[((0*8+ci)*3+ky)*3+kx], r0);
          r1 = fmaf(v, rw2[((1*8+ci)*3+ky)*3+kx], r1);
          r2 = fmaf(v, rw2[((2*8+ci)*3+ky)*3+kx], r2);
        }
      }
    }
    size_t gi = (size_t)gy*IW + gx;
    float j0 = sJ[0][(iy+2)*RD1 + ix+2];
    float j1 = sJ[1][(iy+2)*RD1 + ix+2];
    float j2 = sJ[2][(iy+2)*RD1 + ix+2];
    out[((size_t)b*3+0)*HW + gi] = 0.5f*(j0 + 0.2f*r0) + 0.5f*clip01(xb[gi]);
    out[((size_t)b*3+1)*HW + gi] = 0.5f*(j1 + 0.2f*r1) + 0.5f*clip01(xb[HW+gi]);
    out[((size_t)b*3+2)*HW + gi] = 0.5f*(j2 + 0.2f*r2) + 0.5f*clip01(xb[2*(size_t)HW+gi]);
  }
}

// ---------------- histogram (256 bins, valid-mask weights) ----------------
__global__ __launch_bounds__(256) void k_hist(const float* __restrict__ r, unsigned* __restrict__ hist)
{
  __shared__ unsigned lh[256];
  const int slice = blockIdx.y;
  const int t = threadIdx.x;
  lh[t] = 0u; __syncthreads();
  const float4* p = (const float4*)(r + (size_t)slice*HW);
  int stride = gridDim.x*blockDim.x;
  for (int i = blockIdx.x*blockDim.x + t; i < HW/4; i += stride) {
    float4 v = p[i];
    float a[4] = {v.x, v.y, v.z, v.w};
#pragma unroll
    for (int q = 0; q < 4; ++q) {
      float vv = a[q];
      if (vv >= 0.f && vv <= 1.f) {
        int bin = (int)floorf(vv*256.f);
        bin = min(max(bin, 0), 255);
        atomicAdd(&lh[bin], 1u);
      }
    }
  }
  __syncthreads();
  if (lh[t]) atomicAdd(&hist[slice*256 + t], lh[t]);
}

// ---------------- cdf -> lut (one block per slice; exact integer-float scan) ----------------
__global__ void k_cdf(const unsigned* __restrict__ hist, float* __restrict__ lut)
{
  __shared__ float sc[256];
  const int s = blockIdx.x;
  const int t = threadIdx.x;
  sc[t] = (float)hist[s*256 + t];
  __syncthreads();
  for (int off = 1; off < 256; off <<= 1) {
    float add = (t >= off) ? sc[t-off] : 0.f;
    __syncthreads();
    sc[t] += add;
    __syncthreads();
  }
  float total = sc[255];
  lut[s*256 + t] = fminf(fmaxf(sc[t]/total, 0.f), 1.f);
}

// ---------------- apply LUT in-place + per-(b,c) min/max ----------------
__global__ __launch_bounds__(256) void k_apply(float* r, const float* __restrict__ lut,
    unsigned* __restrict__ mnb, unsigned* __restrict__ mxb)
{
  __shared__ float slut[256];
  __shared__ float smn[256], smx[256];
  const int slice = blockIdx.y;
  const int t = threadIdx.x;
  slut[t] = lut[slice*256 + t];
  __syncthreads();
  float lmn = 3.4e38f, lmx = -3.4e38f;
  float4* p = (float4*)(r + (size_t)slice*HW);
  int stride = gridDim.x*blockDim.x;
  for (int i = blockIdx.x*blockDim.x + t; i < HW/4; i += stride) {
    float4 v = p[i];
    float o0 = slut[min(max((int)(v.x*255.f), 0), 255)];
    float o1 = slut[min(max((int)(v.y*255.f), 0), 255)];
    float o2 = slut[min(max((int)(v.z*255.f), 0), 255)];
    float o3 = slut[min(max((int)(v.w*255.f), 0), 255)];
    lmn = fminf(lmn, fminf(fminf(o0,o1), fminf(o2,o3)));
    lmx = fmaxf(lmx, fmaxf(fmaxf(o0,o1), fmaxf(o2,o3)));
    float4 ov = {o0,o1,o2,o3};
    p[i] = ov;
  }
  smn[t] = lmn; smx[t] = lmx; __syncthreads();
  for (int s = 128; s > 0; s >>= 1) {
    if (t < s) { smn[t] = fminf(smn[t], smn[t+s]); smx[t] = fmaxf(smx[t], smx[t+s]); }
    __syncthreads();
  }
  if (t == 0) {
    atomicMin(&mnb[slice], __float_as_uint(smn[0]));
    atomicMax(&mxb[slice], __float_as_uint(smx[0]));
  }
}

// ---------------- stretch + saturation + sigmoid, in place ----------------
__global__ __launch_bounds__(256) void k_final(float* r,
    const unsigned* __restrict__ mnb, const unsigned* __restrict__ mxb)
{
  const int b = blockIdx.y;
  float mn[3], mx[3];
#pragma unroll
  for (int c = 0; c < 3; ++c) { mn[c] = __uint_as_float(mnb[b*3+c]); mx[c] = __uint_as_float(mxb[b*3+c]); }
  int stride = gridDim.x*blockDim.x;
  for (int i = blockIdx.x*blockDim.x + threadIdx.x; i < HW/4; i += stride) {
    float4 v[3];
#pragma unroll
    for (int c = 0; c < 3; ++c) v[c] = ((const float4*)(r + ((size_t)b*3+c)*HW))[i];
    float* f0 = (float*)&v[0]; float* f1 = (float*)&v[1]; float* f2 = (float*)&v[2];
#pragma unroll
    for (int q = 0; q < 4; ++q) {
      float rr[3] = { f0[q], f1[q], f2[q] };
#pragma unroll
      for (int c = 0; c < 3; ++c) {
        float d = mx[c] - mn[c];
        if (d > 0.05f) rr[c] = (rr[c] - mn[c]) / fmaxf(d, 0.05f) * 0.95f;
      }
      float m = (rr[0] + rr[1] + rr[2]) / 3.f;
#pragma unroll
      for (int c = 0; c < 3; ++c) {
        float s = m + 1.3f*(rr[c] - m);
        float o = 1.f/(1.f + expf(-(s - 0.5f)*5.f))*0.95f + 0.025f;
        rr[c] = clip01(o);
      }
      f0[q] = rr[0]; f1[q] = rr[1]; f2[q] = rr[2];
    }
#pragma unroll
    for (int c = 0; c < 3; ++c) ((float4*)(r + ((size_t)b*3+c)*HW))[i] = v[c];
  }
}

extern "C" void kernel_launch(void* const* d_in, const int* in_sizes, int n_in,
                              void* d_out, int out_size, void* d_ws, size_t ws_size,
                              hipStream_t stream) {
  const float* x   = (const float*)d_in[0];
  const float* w1  = (const float*)d_in[1];  const float* b1 = (const float*)d_in[2];
  const float* w2  = (const float*)d_in[3];  const float* b2 = (const float*)d_in[4];
  const float* w3  = (const float*)d_in[5];  const float* b3 = (const float*)d_in[6];
  const float* w4  = (const float*)d_in[7];  const float* b4 = (const float*)d_in[8];
  const float* w5  = (const float*)d_in[9];  const float* b5 = (const float*)d_in[10];
  const float* rw1 = (const float*)d_in[11]; const float* rb1 = (const float*)d_in[12];
  const float* rw2 = (const float*)d_in[13]; const float* rb2 = (const float*)d_in[14];
  float* out = (float*)d_out;

  float* ws = (float*)d_ws;
  float* kbuf   = ws;                                   // B*3*HW
  float* bright = kbuf + (size_t)NBATCH*3*HW;           // B*HW
  float* overall = bright + (size_t)NBATCH*HW;          // B
  float* sum_gt  = overall + NBATCH;                    // B*3
  float* Abuf    = sum_gt + NBATCH*3;                   // B*3
  float* lut     = Abuf + NBATCH*3;                     // 24*256
  unsigned* hr      = (unsigned*)(lut + NBATCH*3*256);  // 4*B*256
  unsigned* prefix  = hr + 4*NBATCH*256;                // B
  unsigned* remain  = prefix + NBATCH;                  // B
  unsigned* tie_cnt = remain + NBATCH;                  // B
  unsigned* tie_idx = tie_cnt + NBATCH;                 // B*TIE_CAP
  unsigned* histeq  = tie_idx + NBATCH*TIE_CAP;         // 24*256
  unsigned* mnb     = histeq + NBATCH*3*256;            // 24
  unsigned* mxb     = mnb + NBATCH*3;                   // 24

  k_init<<<1, 256, 0, stream>>>(hr, prefix, remain, overall, tie_cnt, sum_gt, histeq, mnb, mxb);
  k_bright<<<dim3(1024, NBATCH), 256, 0, stream>>>(x, bright, overall);
  k_trunk<<<dim3((IW+TTS-1)/TTS, (IH+TTS-1)/TTS, NBATCH), 256, 0, stream>>>(
      x, w1, b1, w2, b2, w3, b3, w4, b4, w5, b5, kbuf);
  for (int p = 0; p < 4; ++p) {
    k_radix_hist<<<dim3(64, NBATCH), 256, 0, stream>>>(bright, prefix, hr, p);
    k_radix_scan<<<1, 64, 0, stream>>>(hr, prefix, remain, p);
  }
  k_gather<<<dim3(128, NBATCH), 256, 0, stream>>>(x, bright, prefix, sum_gt, tie_cnt, tie_idx);
  k_afinal<<<NBATCH, 256, 0, stream>>>(x, sum_gt, tie_cnt, tie_idx, remain, overall, Abuf);
  k_refineJ<<<dim3(IW/RTS, IH/RTS, NBATCH), 256, 0, stream>>>(
      x, kbuf, Abuf, rw1, rb1, rw2, rb2, out);
  k_hist<<<dim3(64, NBATCH*3), 256, 0, stream>>>(out, histeq);
  k_cdf<<<NBATCH*3, 256, 0, stream>>>(histeq, lut);
  k_apply<<<dim3(64, NBATCH*3), 256, 0, stream>>>(out, lut, mnb, mxb);
  k_final<<<dim3(128, NBATCH), 256, 0, stream>>>(out, mnb, mxb);
}

// Round 5
// 1851.574 us; speedup vs baseline: 4.7487x; 4.7487x over previous
//
#include <hip/hip_runtime.h>
#include <math.h>

#define NBATCH 8
#define IH 1024
#define IW 1024
#define HW (IH*IW)
#define NTOP 1048
#define TIE_CAP 4096

// trunk tiling: output tile TTS x TTS, halos 7/6/4/1 for x1/x2/x3/x4.
#define TTS 18
#define TD1 (TTS+14)  // 32
#define TD2 (TTS+12)  // 30
#define TD3 (TTS+8)   // 26
#define TD4 (TTS+2)   // 20
// odd row strides -> bank-conflict-free (gcd(stride,32)=1)
#define SD1 33
#define SD2 31
#define SD3 27
#define SD4 21
// per-channel sizes (padded +4 so last-strip vector over-reads stay in-array)
#define CH1 (SD1*TD1+4)
#define CH2 (SD2*TD2+4)
#define CH3 (SD3*TD3+4)
#define CH4 (SD4*TD4+4)

// refinement tiling
#define RTS 32
#define RD1 (RTS+4)   // 36
#define RD2 (RTS+2)   // 34

__device__ __forceinline__ float clip01(float v){ return fminf(fmaxf(v, 0.f), 1.f); }

// accumulate KSxKS windows for a 1x4 output strip over 3 source channels.
// ci/ky are RUNTIME loops (unroll 1): caps the live set at ~50 VGPR
// (a[12] + v[KS+3] + 3*KS weights) -> no spills. Weights come via s_load
// (uniform address, scalar pipe); activations via ds_read (LDS pipe);
// the VALU sees almost pure v_fmac_f32.
template<int CH,int SD,int KS,int CIN>
__device__ __forceinline__ void accrow4(float a[3][4], const float (*sx)[CH],
    int base, const float* __restrict__ w, int ci0)
{
#pragma unroll 1
  for (int ci = 0; ci < 3; ++ci) {
#pragma unroll 1
    for (int ky = 0; ky < KS; ++ky) {
      float v[KS+3];
      const float* row = &sx[ci][base + ky*SD];
#pragma unroll
      for (int j = 0; j < KS+3; ++j) v[j] = row[j];
#pragma unroll
      for (int o = 0; o < 3; ++o) {
        const float* wp = w + ((o*CIN + ci0+ci)*KS + ky)*KS;
#pragma unroll
        for (int kx = 0; kx < KS; ++kx) {
          float wv = wp[kx];
#pragma unroll
          for (int q = 0; q < 4; ++q)
            a[o][q] = fmaf(v[kx+q], wv, a[o][q]);
        }
      }
    }
  }
}

// ---------------- init small scratch ----------------
__global__ void k_init(unsigned* hr, unsigned* prefix, unsigned* remain,
                       float* overall, unsigned* tie_cnt, float* sum_gt,
                       unsigned* histeq, unsigned* mnb, unsigned* mxb)
{
  int t = threadIdx.x;
  for (int i = t; i < 4*NBATCH*256; i += 256) hr[i] = 0u;
  for (int i = t; i < NBATCH*3*256; i += 256) histeq[i] = 0u;
  if (t < NBATCH) { prefix[t] = 0u; remain[t] = NTOP; overall[t] = 0.f; tie_cnt[t] = 0u; }
  if (t < NBATCH*3) { sum_gt[t] = 0.f; mnb[t] = 0x7f7fffffu; mxb[t] = 0u; }
}

// ---------------- bright = mean_c(clip(x)), overall sum ----------------
__global__ __launch_bounds__(256) void k_bright(const float* __restrict__ x,
    float* __restrict__ bright, float* __restrict__ overall)
{
  __shared__ float sred[256];
  const int b = blockIdx.y;
  const int t = threadIdx.x;
  const float4* c0 = (const float4*)(x + (size_t)b*3*HW);
  const float4* c1 = (const float4*)(x + (size_t)b*3*HW + HW);
  const float4* c2 = (const float4*)(x + (size_t)b*3*HW + 2*(size_t)HW);
  float4* bp = (float4*)(bright + (size_t)b*HW);
  float lsum = 0.f;
  int stride = gridDim.x*blockDim.x;
  for (int i = blockIdx.x*blockDim.x + t; i < HW/4; i += stride) {
    float4 a = c0[i], d = c1[i], e = c2[i];
    float4 br;
    br.x = (clip01(a.x)+clip01(d.x)+clip01(e.x))/3.f;
    br.y = (clip01(a.y)+clip01(d.y)+clip01(e.y))/3.f;
    br.z = (clip01(a.z)+clip01(d.z)+clip01(e.z))/3.f;
    br.w = (clip01(a.w)+clip01(d.w)+clip01(e.w))/3.f;
    bp[i] = br;
    lsum += br.x+br.y+br.z+br.w;
  }
  sred[t] = lsum; __syncthreads();
  for (int s = 128; s > 0; s >>= 1) { if (t < s) sred[t] += sred[t+s]; __syncthreads(); }
  if (t == 0) atomicAdd(&overall[b], sred[0]);
}

// ---------------- fused conv trunk: x -> k ----------------
__global__ __launch_bounds__(256) void k_trunk(const float* __restrict__ x,
    const float* __restrict__ w1, const float* __restrict__ b1,
    const float* __restrict__ w2, const float* __restrict__ b2,
    const float* __restrict__ w3, const float* __restrict__ b3,
    const float* __restrict__ w4, const float* __restrict__ b4,
    const float* __restrict__ w5, const float* __restrict__ b5,
    float* __restrict__ kout)
{
  __shared__ float s1[3][CH1];
  __shared__ float s2[3][CH2];
  __shared__ float s3[3][CH3];
  __shared__ float s4[3][CH4];
  const int b = blockIdx.z;
  const int gy0 = blockIdx.y*TTS, gx0 = blockIdx.x*TTS;
  const float* xb = x + (size_t)b*3*HW;
  const int tid = threadIdx.x;

  // stage 1: x1 = relu(1x1 conv of clip(x)); zero outside image.
  for (int idx = tid; idx < TD1*TD1; idx += 256) {
    int iy = idx/TD1, ix = idx - iy*TD1;
    int gy = gy0 - 7 + iy, gx = gx0 - 7 + ix;
    float o0 = 0.f, o1 = 0.f, o2 = 0.f;
    if (gy >= 0 && gy < IH && gx >= 0 && gx < IW) {
      int gi = gy*IW + gx;
      float c0 = clip01(xb[gi]), c1 = clip01(xb[HW+gi]), c2 = clip01(xb[2*HW+gi]);
      o0 = fmaxf(fmaf(w1[0],c0,fmaf(w1[1],c1,fmaf(w1[2],c2,b1[0]))), 0.f);
      o1 = fmaxf(fmaf(w1[3],c0,fmaf(w1[4],c1,fmaf(w1[5],c2,b1[1]))), 0.f);
      o2 = fmaxf(fmaf(w1[6],c0,fmaf(w1[7],c1,fmaf(w1[8],c2,b1[2]))), 0.f);
    }
    int off = iy*SD1 + ix;
    s1[0][off]=o0; s1[1][off]=o1; s1[2][off]=o2;
  }
  __syncthreads();

  // stage 2: x2 = relu(3x3 conv of x1), CIN=3. 240 units, single strip/thread.
  {
    const int NU = ((TD2+3)/4)*TD2;  // 240
    int u = tid;
    if (u < NU) {
      int iy = u % TD2, ix0 = (u / TD2)*4;
      int gy = gy0 - 6 + iy;
      float a[3][4];
#pragma unroll
      for (int o=0;o<3;++o){float bv=b2[o];a[o][0]=bv;a[o][1]=bv;a[o][2]=bv;a[o][3]=bv;}
      accrow4<CH1,SD1,3,3>(a, s1, iy*SD1 + ix0, w2, 0);
      bool rowok = (gy >= 0 && gy < IH);
#pragma unroll
      for (int q=0;q<4;++q) {
        int ix = ix0+q;
        if (ix < TD2) {
          int gx = gx0 - 6 + ix;
          bool ok = rowok && gx >= 0 && gx < IW;
          int off = iy*SD2 + ix;
          s2[0][off] = ok ? fmaxf(a[0][q],0.f) : 0.f;
          s2[1][off] = ok ? fmaxf(a[1][q],0.f) : 0.f;
          s2[2][off] = ok ? fmaxf(a[2][q],0.f) : 0.f;
        }
      }
    }
  }
  __syncthreads();

  // stage 3: x3 = relu(5x5 conv of [x1,x2]), CIN=6. 182 units.
  {
    const int NU = ((TD3+3)/4)*TD3;  // 182
    int u = tid;
    if (u < NU) {
      int iy = u % TD3, ix0 = (u / TD3)*4;
      int gy = gy0 - 4 + iy;
      float a[3][4];
#pragma unroll
      for (int o=0;o<3;++o){float bv=b3[o];a[o][0]=bv;a[o][1]=bv;a[o][2]=bv;a[o][3]=bv;}
      accrow4<CH1,SD1,5,6>(a, s1, (iy+1)*SD1 + (ix0+1), w3, 0);
      accrow4<CH2,SD2,5,6>(a, s2, iy*SD2 + ix0,         w3, 3);
      bool rowok = (gy >= 0 && gy < IH);
#pragma unroll
      for (int q=0;q<4;++q) {
        int ix = ix0+q;
        if (ix < TD3) {
          int gx = gx0 - 4 + ix;
          bool ok = rowok && gx >= 0 && gx < IW;
          int off = iy*SD3 + ix;
          s3[0][off] = ok ? fmaxf(a[0][q],0.f) : 0.f;
          s3[1][off] = ok ? fmaxf(a[1][q],0.f) : 0.f;
          s3[2][off] = ok ? fmaxf(a[2][q],0.f) : 0.f;
        }
      }
    }
  }
  __syncthreads();

  // stage 4: x4 = relu(7x7 conv of [x2,x3]), CIN=6. 100 units.
  {
    const int NU = ((TD4+3)/4)*TD4;  // 100
    int u = tid;
    if (u < NU) {
      int iy = u % TD4, ix0 = (u / TD4)*4;
      int gy = gy0 - 1 + iy;
      float a[3][4];
#pragma unroll
      for (int o=0;o<3;++o){float bv=b4[o];a[o][0]=bv;a[o][1]=bv;a[o][2]=bv;a[o][3]=bv;}
      accrow4<CH2,SD2,7,6>(a, s2, (iy+2)*SD2 + (ix0+2), w4, 0);
      accrow4<CH3,SD3,7,6>(a, s3, iy*SD3 + ix0,         w4, 3);
      bool rowok = (gy >= 0 && gy < IH);
#pragma unroll
      for (int q=0;q<4;++q) {
        int ix = ix0+q;
        if (ix < TD4) {
          int gx = gx0 - 1 + ix;
          bool ok = rowok && gx >= 0 && gx < IW;
          int off = iy*SD4 + ix;
          s4[0][off] = ok ? fmaxf(a[0][q],0.f) : 0.f;
          s4[1][off] = ok ? fmaxf(a[1][q],0.f) : 0.f;
          s4[2][off] = ok ? fmaxf(a[2][q],0.f) : 0.f;
        }
      }
    }
  }
  __syncthreads();

  // stage 5: k = clip(relu(3x3 conv of [x1,x2,x3,x4]), 0.05, 2). 90 units.
  {
    const int NU = ((TTS+3)/4)*TTS;  // 90
    int u = tid;
    if (u < NU) {
      int iy = u % TTS, ix0 = (u / TTS)*4;
      int gy = gy0 + iy;
      float a[3][4];
#pragma unroll
      for (int o=0;o<3;++o){float bv=b5[o];a[o][0]=bv;a[o][1]=bv;a[o][2]=bv;a[o][3]=bv;}
      accrow4<CH1,SD1,3,12>(a, s1, (iy+6)*SD1 + (ix0+6), w5, 0);
      accrow4<CH2,SD2,3,12>(a, s2, (iy+5)*SD2 + (ix0+5), w5, 3);
      accrow4<CH3,SD3,3,12>(a, s3, (iy+3)*SD3 + (ix0+3), w5, 6);
      accrow4<CH4,SD4,3,12>(a, s4, iy*SD4 + ix0,         w5, 9);
      if (gy < IH) {
#pragma unroll
        for (int q=0;q<4;++q) {
          int ix = ix0+q;
          int gx = gx0 + ix;
          if (ix < TTS && gx < IW) {
            size_t gi = (size_t)gy*IW + gx;
            kout[((size_t)b*3+0)*HW + gi] = fminf(fmaxf(a[0][q], 0.05f), 2.0f);
            kout[((size_t)b*3+1)*HW + gi] = fminf(fmaxf(a[1][q], 0.05f), 2.0f);
            kout[((size_t)b*3+2)*HW + gi] = fminf(fmaxf(a[2][q], 0.05f), 2.0f);
          }
        }
      }
    }
  }
}

// ---------------- radix select (top-NTOP threshold) ----------------
__global__ __launch_bounds__(256) void k_radix_hist(const float* __restrict__ bright,
    const unsigned* __restrict__ prefix, unsigned* __restrict__ hr, int pass)
{
  __shared__ unsigned lh[256];
  const int b = blockIdx.y;
  const int t = threadIdx.x;
  lh[t] = 0u; __syncthreads();
  const unsigned pf = prefix[b];
  const unsigned mask = (pass == 0) ? 0u : (0xFFFFFFFFu << (32 - 8*pass));
  const int shift = 24 - 8*pass;
  const float* br = bright + (size_t)b*HW;
  int stride = gridDim.x*blockDim.x;
  for (int i = blockIdx.x*blockDim.x + t; i < HW; i += stride) {
    unsigned bits = __float_as_uint(br[i]);
    if ((bits & mask) == pf) atomicAdd(&lh[(bits >> shift) & 0xFFu], 1u);
  }
  __syncthreads();
  if (lh[t]) atomicAdd(&hr[(pass*NBATCH + b)*256 + t], lh[t]);
}

__global__ void k_radix_scan(const unsigned* __restrict__ hr,
    unsigned* __restrict__ prefix, unsigned* __restrict__ remain, int pass)
{
  int b = threadIdx.x;
  if (b >= NBATCH) return;
  unsigned rem = remain[b];
  const unsigned* h = hr + (pass*NBATCH + b)*256;
  const int shift = 24 - 8*pass;
  for (int bin = 255; bin >= 0; --bin) {
    unsigned c = h[bin];
    if (rem <= c) { prefix[b] |= ((unsigned)bin) << shift; remain[b] = rem; return; }
    rem -= c;
  }
  remain[b] = rem;
}

// ---------------- gather colors of pixels above/equal threshold ----------------
__global__ __launch_bounds__(256) void k_gather(const float* __restrict__ x,
    const float* __restrict__ bright, const unsigned* __restrict__ prefix,
    float* __restrict__ sum_gt, unsigned* __restrict__ tie_cnt, unsigned* __restrict__ tie_idx)
{
  const int b = blockIdx.y;
  const unsigned T = prefix[b];
  const float* br = bright + (size_t)b*HW;
  int stride = gridDim.x*blockDim.x;
  for (int i = blockIdx.x*blockDim.x + threadIdx.x; i < HW; i += stride) {
    unsigned bits = __float_as_uint(br[i]);
    if (bits > T) {
#pragma unroll
      for (int c = 0; c < 3; ++c)
        atomicAdd(&sum_gt[b*3+c], clip01(x[((size_t)b*3+c)*HW + i]));
    } else if (bits == T) {
      unsigned p = atomicAdd(&tie_cnt[b], 1u);
      if (p < TIE_CAP) tie_idx[b*TIE_CAP + p] = i;
    }
  }
}

// ---------------- finalize A (lowest-index tie-break like lax.top_k) ----------------
__global__ __launch_bounds__(256) void k_afinal(const float* __restrict__ x,
    const float* __restrict__ sum_gt, const unsigned* __restrict__ tie_cnt,
    const unsigned* __restrict__ tie_idx, const unsigned* __restrict__ remain,
    const float* __restrict__ overall, float* __restrict__ A)
{
  __shared__ unsigned sidx[TIE_CAP];
  __shared__ unsigned sred[256];
  __shared__ float ssum[3];
  const int b = blockIdx.x;
  const int t = threadIdx.x;
  unsigned cnt = tie_cnt[b]; if (cnt > TIE_CAP) cnt = TIE_CAP;
  unsigned need = remain[b]; if (need > cnt) need = cnt;
  if (t < 3) ssum[t] = 0.f;
  for (unsigned i = t; i < cnt; i += 256) sidx[i] = tie_idx[b*TIE_CAP + i];
  __syncthreads();
  if (need == cnt) {
    float l0=0.f,l1=0.f,l2=0.f;
    for (unsigned i = t; i < cnt; i += 256) {
      unsigned px = sidx[i];
      l0 += clip01(x[((size_t)b*3+0)*HW + px]);
      l1 += clip01(x[((size_t)b*3+1)*HW + px]);
      l2 += clip01(x[((size_t)b*3+2)*HW + px]);
    }
    atomicAdd(&ssum[0], l0); atomicAdd(&ssum[1], l1); atomicAdd(&ssum[2], l2);
    __syncthreads();
  } else {
    for (unsigned it = 0; it < need; ++it) {
      unsigned lmin = 0xFFFFFFFFu;
      for (unsigned i = t; i < cnt; i += 256) lmin = min(lmin, sidx[i]);
      sred[t] = lmin; __syncthreads();
      for (int s = 128; s > 0; s >>= 1) { if (t < s) sred[t] = min(sred[t], sred[t+s]); __syncthreads(); }
      unsigned mv = sred[0];
      if (t == 0) {
        ssum[0] += clip01(x[((size_t)b*3+0)*HW + mv]);
        ssum[1] += clip01(x[((size_t)b*3+1)*HW + mv]);
        ssum[2] += clip01(x[((size_t)b*3+2)*HW + mv]);
      }
      for (unsigned i = t; i < cnt; i += 256) if (sidx[i] == mv) sidx[i] = 0xFFFFFFFFu;
      __syncthreads();
    }
  }
  __syncthreads();
  if (t < 3) {
    float a = (sum_gt[b*3+t] + ssum[t]) / (float)NTOP;
    float f = fminf(fmaxf(1.2f - overall[b]/(float)HW, 0.8f), 1.5f);
    A[b*3+t] = fminf(fmaxf(a*f, 0.5f), 0.95f);
  }
}

// ---------------- fused J + refinement (3->8->3, 3x3) + blend ----------------
__global__ __launch_bounds__(256) void k_refineJ(const float* __restrict__ x,
    const float* __restrict__ kin, const float* __restrict__ A,
    const float* __restrict__ rw1, const float* __restrict__ rb1,
    const float* __restrict__ rw2, const float* __restrict__ rb2,
    float* __restrict__ out)
{
  __shared__ float sJ[3][RD1*RD1];
  __shared__ float sH[8][RD2*RD2];
  const int b = blockIdx.z;
  const int gy0 = blockIdx.y*RTS, gx0 = blockIdx.x*RTS;
  const int tid = threadIdx.x;
  const float A0 = A[b*3+0], A1 = A[b*3+1], A2 = A[b*3+2];
  const float* xb = x + (size_t)b*3*HW;
  const float* kb = kin + (size_t)b*3*HW;

  for (int idx = tid; idx < RD1*RD1; idx += 256) {
    int iy = idx/RD1, ix = idx - iy*RD1;
    int gy = gy0 - 2 + iy, gx = gx0 - 2 + ix;
    float j0 = 0.f, j1 = 0.f, j2 = 0.f;
    if (gy >= 0 && gy < IH && gx >= 0 && gx < IW) {
      size_t gi = (size_t)gy*IW + gx;
      float c0 = clip01(xb[gi]), c1 = clip01(xb[HW+gi]), c2 = clip01(xb[2*(size_t)HW+gi]);
      float br = (c0+c1+c2)/3.f;
      float st = fminf(fmaxf(1.f-br, 0.3f), 0.8f);
      float t0 = fminf(fmaxf(1.f-st*kb[gi],             0.1f),1.f)+1e-5f;
      float t1 = fminf(fmaxf(1.f-st*kb[HW+gi],          0.1f),1.f)+1e-5f;
      float t2 = fminf(fmaxf(1.f-st*kb[2*(size_t)HW+gi],0.1f),1.f)+1e-5f;
      j0 = (c0-A0)/t0 + A0;
      j1 = (c1-A1)/t1 + A1;
      j2 = (c2-A2)/t2 + A2;
    }
    sJ[0][idx]=j0; sJ[1][idx]=j1; sJ[2][idx]=j2;
  }
  __syncthreads();

  for (int idx = tid; idx < RD2*RD2; idx += 256) {
    int iy = idx/RD2, ix = idx - iy*RD2;
    int gy = gy0 - 1 + iy, gx = gx0 - 1 + ix;
    float acc[8];
#pragma unroll
    for (int o = 0; o < 8; ++o) acc[o] = rb1[o];
    if (gy >= 0 && gy < IH && gx >= 0 && gx < IW) {
#pragma unroll
      for (int ci = 0; ci < 3; ++ci) {
#pragma unroll
        for (int ky = 0; ky < 3; ++ky) {
#pragma unroll
          for (int kx = 0; kx < 3; ++kx) {
            float v = sJ[ci][(iy+ky)*RD1 + ix+kx];
#pragma unroll
            for (int o = 0; o < 8; ++o)
              acc[o] = fmaf(v, rw1[((o*3+ci)*3+ky)*3+kx], acc[o]);
          }
        }
      }
#pragma unroll
      for (int o = 0; o < 8; ++o) sH[o][idx] = fmaxf(acc[o], 0.f);
    } else {
#pragma unroll
      for (int o = 0; o < 8; ++o) sH[o][idx] = 0.f;
    }
  }
  __syncthreads();

  for (int idx = tid; idx < RTS*RTS; idx += 256) {
    int iy = idx/RTS, ix = idx - iy*RTS;
    int gy = gy0 + iy, gx = gx0 + ix;
    float r0 = rb2[0], r1 = rb2[1], r2 = rb2[2];
#pragma unroll
    for (int ci = 0; ci < 8; ++ci) {
#pragma unroll
      for (int ky = 0; ky < 3; ++ky) {
#pragma unroll
        for (int kx = 0; kx < 3; ++kx) {
          float v = sH[ci][(iy+ky)*RD2 + ix+kx];
          r0 = fmaf(v, rw2[((0*8+ci)*3+ky)*3+kx], r0);
          r1 = fmaf(v, rw2[((1*8+ci)*3+ky)*3+kx], r1);
          r2 = fmaf(v, rw2[((2*8+ci)*3+ky)*3+kx], r2);
        }
      }
    }
    size_t gi = (size_t)gy*IW + gx;
    float j0 = sJ[0][(iy+2)*RD1 + ix+2];
    float j1 = sJ[1][(iy+2)*RD1 + ix+2];
    float j2 = sJ[2][(iy+2)*RD1 + ix+2];
    out[((size_t)b*3+0)*HW + gi] = 0.5f*(j0 + 0.2f*r0) + 0.5f*clip01(xb[gi]);
    out[((size_t)b*3+1)*HW + gi] = 0.5f*(j1 + 0.2f*r1) + 0.5f*clip01(xb[HW+gi]);
    out[((size_t)b*3+2)*HW + gi] = 0.5f*(j2 + 0.2f*r2) + 0.5f*clip01(xb[2*(size_t)HW+gi]);
  }
}

// ---------------- histogram (256 bins, valid-mask weights) ----------------
__global__ __launch_bounds__(256) void k_hist(const float* __restrict__ r, unsigned* __restrict__ hist)
{
  __shared__ unsigned lh[256];
  const int slice = blockIdx.y;
  const int t = threadIdx.x;
  lh[t] = 0u; __syncthreads();
  const float4* p = (const float4*)(r + (size_t)slice*HW);
  int stride = gridDim.x*blockDim.x;
  for (int i = blockIdx.x*blockDim.x + t; i < HW/4; i += stride) {
    float4 v = p[i];
    float a[4] = {v.x, v.y, v.z, v.w};
#pragma unroll
    for (int q = 0; q < 4; ++q) {
      float vv = a[q];
      if (vv >= 0.f && vv <= 1.f) {
        int bin = (int)floorf(vv*256.f);
        bin = min(max(bin, 0), 255);
        atomicAdd(&lh[bin], 1u);
      }
    }
  }
  __syncthreads();
  if (lh[t]) atomicAdd(&hist[slice*256 + t], lh[t]);
}

// ---------------- cdf -> lut (one block per slice; exact integer-float scan) ----------------
__global__ void k_cdf(const unsigned* __restrict__ hist, float* __restrict__ lut)
{
  __shared__ float sc[256];
  const int s = blockIdx.x;
  const int t = threadIdx.x;
  sc[t] = (float)hist[s*256 + t];
  __syncthreads();
  for (int off = 1; off < 256; off <<= 1) {
    float add = (t >= off) ? sc[t-off] : 0.f;
    __syncthreads();
    sc[t] += add;
    __syncthreads();
  }
  float total = sc[255];
  lut[s*256 + t] = fminf(fmaxf(sc[t]/total, 0.f), 1.f);
}

// ---------------- apply LUT in-place + per-(b,c) min/max ----------------
__global__ __launch_bounds__(256) void k_apply(float* r, const float* __restrict__ lut,
    unsigned* __restrict__ mnb, unsigned* __restrict__ mxb)
{
  __shared__ float slut[256];
  __shared__ float smn[256], smx[256];
  const int slice = blockIdx.y;
  const int t = threadIdx.x;
  slut[t] = lut[slice*256 + t];
  __syncthreads();
  float lmn = 3.4e38f, lmx = -3.4e38f;
  float4* p = (float4*)(r + (size_t)slice*HW);
  int stride = gridDim.x*blockDim.x;
  for (int i = blockIdx.x*blockDim.x + t; i < HW/4; i += stride) {
    float4 v = p[i];
    float o0 = slut[min(max((int)(v.x*255.f), 0), 255)];
    float o1 = slut[min(max((int)(v.y*255.f), 0), 255)];
    float o2 = slut[min(max((int)(v.z*255.f), 0), 255)];
    float o3 = slut[min(max((int)(v.w*255.f), 0), 255)];
    lmn = fminf(lmn, fminf(fminf(o0,o1), fminf(o2,o3)));
    lmx = fmaxf(lmx, fmaxf(fmaxf(o0,o1), fmaxf(o2,o3)));
    float4 ov = {o0,o1,o2,o3};
    p[i] = ov;
  }
  smn[t] = lmn; smx[t] = lmx; __syncthreads();
  for (int s = 128; s > 0; s >>= 1) {
    if (t < s) { smn[t] = fminf(smn[t], smn[t+s]); smx[t] = fmaxf(smx[t], smx[t+s]); }
    __syncthreads();
  }
  if (t == 0) {
    atomicMin(&mnb[slice], __float_as_uint(smn[0]));
    atomicMax(&mxb[slice], __float_as_uint(smx[0]));
  }
}

// ---------------- stretch + saturation + sigmoid, in place ----------------
__global__ __launch_bounds__(256) void k_final(float* r,
    const unsigned* __restrict__ mnb, const unsigned* __restrict__ mxb)
{
  const int b = blockIdx.y;
  float mn[3], mx[3];
#pragma unroll
  for (int c = 0; c < 3; ++c) { mn[c] = __uint_as_float(mnb[b*3+c]); mx[c] = __uint_as_float(mxb[b*3+c]); }
  int stride = gridDim.x*blockDim.x;
  for (int i = blockIdx.x*blockDim.x + threadIdx.x; i < HW/4; i += stride) {
    float4 v[3];
#pragma unroll
    for (int c = 0; c < 3; ++c) v[c] = ((const float4*)(r + ((size_t)b*3+c)*HW))[i];
    float* f0 = (float*)&v[0]; float* f1 = (float*)&v[1]; float* f2 = (float*)&v[2];
#pragma unroll
    for (int q = 0; q < 4; ++q) {
      float rr[3] = { f0[q], f1[q], f2[q] };
#pragma unroll
      for (int c = 0; c < 3; ++c) {
        float d = mx[c] - mn[c];
        if (d > 0.05f) rr[c] = (rr[c] - mn[c]) / fmaxf(d, 0.05f) * 0.95f;
      }
      float m = (rr[0] + rr[1] + rr[2]) / 3.f;
#pragma unroll
      for (int c = 0; c < 3; ++c) {
        float s = m + 1.3f*(rr[c] - m);
        float o = 1.f/(1.f + expf(-(s - 0.5f)*5.f))*0.95f + 0.025f;
        rr[c] = clip01(o);
      }
      f0[q] = rr[0]; f1[q] = rr[1]; f2[q] = rr[2];
    }
#pragma unroll
    for (int c = 0; c < 3; ++c) ((float4*)(r + ((size_t)b*3+c)*HW))[i] = v[c];
  }
}

extern "C" void kernel_launch(void* const* d_in, const int* in_sizes, int n_in,
                              void* d_out, int out_size, void* d_ws, size_t ws_size,
                              hipStream_t stream) {
  const float* x   = (const float*)d_in[0];
  const float* w1  = (const float*)d_in[1];  const float* b1 = (const float*)d_in[2];
  const float* w2  = (const float*)d_in[3];  const float* b2 = (const float*)d_in[4];
  const float* w3  = (const float*)d_in[5];  const float* b3 = (const float*)d_in[6];
  const float* w4  = (const float*)d_in[7];  const float* b4 = (const float*)d_in[8];
  const float* w5  = (const float*)d_in[9];  const float* b5 = (const float*)d_in[10];
  const float* rw1 = (const float*)d_in[11]; const float* rb1 = (const float*)d_in[12];
  const float* rw2 = (const float*)d_in[13]; const float* rb2 = (const float*)d_in[14];
  float* out = (float*)d_out;

  float* ws = (float*)d_ws;
  float* kbuf   = ws;                                   // B*3*HW
  float* bright = kbuf + (size_t)NBATCH*3*HW;           // B*HW
  float* overall = bright + (size_t)NBATCH*HW;          // B
  float* sum_gt  = overall + NBATCH;                    // B*3
  float* Abuf    = sum_gt + NBATCH*3;                   // B*3
  float* lut     = Abuf + NBATCH*3;                     // 24*256
  unsigned* hr      = (unsigned*)(lut + NBATCH*3*256);  // 4*B*256
  unsigned* prefix  = hr + 4*NBATCH*256;                // B
  unsigned* remain  = prefix + NBATCH;                  // B
  unsigned* tie_cnt = remain + NBATCH;                  // B
  unsigned* tie_idx = tie_cnt + NBATCH;                 // B*TIE_CAP
  unsigned* histeq  = tie_idx + NBATCH*TIE_CAP;         // 24*256
  unsigned* mnb     = histeq + NBATCH*3*256;            // 24
  unsigned* mxb     = mnb + NBATCH*3;                   // 24

  k_init<<<1, 256, 0, stream>>>(hr, prefix, remain, overall, tie_cnt, sum_gt, histeq, mnb, mxb);
  k_bright<<<dim3(1024, NBATCH), 256, 0, stream>>>(x, bright, overall);
  k_trunk<<<dim3((IW+TTS-1)/TTS, (IH+TTS-1)/TTS, NBATCH), 256, 0, stream>>>(
      x, w1, b1, w2, b2, w3, b3, w4, b4, w5, b5, kbuf);
  for (int p = 0; p < 4; ++p) {
    k_radix_hist<<<dim3(64, NBATCH), 256, 0, stream>>>(bright, prefix, hr, p);
    k_radix_scan<<<1, 64, 0, stream>>>(hr, prefix, remain, p);
  }
  k_gather<<<dim3(128, NBATCH), 256, 0, stream>>>(x, bright, prefix, sum_gt, tie_cnt, tie_idx);
  k_afinal<<<NBATCH, 256, 0, stream>>>(x, sum_gt, tie_cnt, tie_idx, remain, overall, Abuf);
  k_refineJ<<<dim3(IW/RTS, IH/RTS, NBATCH), 256, 0, stream>>>(
      x, kbuf, Abuf, rw1, rb1, rw2, rb2, out);
  k_hist<<<dim3(64, NBATCH*3), 256, 0, stream>>>(out, histeq);
  k_cdf<<<NBATCH*3, 256, 0, stream>>>(histeq, lut);
  k_apply<<<dim3(64, NBATCH*3), 256, 0, stream>>>(out, lut, mnb, mxb);
  k_final<<<dim3(128, NBATCH), 256, 0, stream>>>(out, mnb, mxb);
}